// Round 1
// baseline (312.424 us; speedup 1.0000x reference)
//
#include <hip/hip_runtime.h>
#include <hip/hip_bf16.h>

#define NEG_SLOPE 0.2f

__device__ __forceinline__ float lrelu(float v) {
    return v > 0.f ? v : NEG_SLOPE * v;
}

// ---------------------------------------------------------------------------
// K1: h1[N,128] = x[N,128] @ W1[128,128]   (fp32 vector GEMM)
// Tile: 32 rows x 128 cols per block of 256 threads; 4x4 register blocking.
// ---------------------------------------------------------------------------
__global__ __launch_bounds__(256) void k1_gemm(const float* __restrict__ x,
                                               const float* __restrict__ W1,
                                               float* __restrict__ h1, int n) {
    __shared__ float xs[32][128];
    const int tid = threadIdx.x;
    const int row0 = blockIdx.x * 32;
    // stage x tile: 32*128 floats = 1024 float4, 4 per thread
    for (int i = 0; i < 4; ++i) {
        int f4 = tid + i * 256;          // 0..1023
        int r = f4 >> 5;                 // 32 float4 per row
        int c = (f4 & 31) * 4;
        int gr = row0 + r;
        float4 v = make_float4(0.f, 0.f, 0.f, 0.f);
        if (gr < n) v = *(const float4*)&x[(size_t)gr * 128 + c];
        *(float4*)&xs[r][c] = v;
    }
    __syncthreads();
    const int tx = tid & 31;             // col group: cols 4*tx..4*tx+3
    const int ty = tid >> 5;             // row group: rows 4*ty..4*ty+3
    float acc[4][4] = {};
#pragma unroll 4
    for (int k = 0; k < 128; ++k) {
        float4 wv = *(const float4*)&W1[k * 128 + tx * 4];
        float xv[4];
#pragma unroll
        for (int r = 0; r < 4; ++r) xv[r] = xs[ty * 4 + r][k];
#pragma unroll
        for (int r = 0; r < 4; ++r) {
            acc[r][0] += xv[r] * wv.x;
            acc[r][1] += xv[r] * wv.y;
            acc[r][2] += xv[r] * wv.z;
            acc[r][3] += xv[r] * wv.w;
        }
    }
#pragma unroll
    for (int r = 0; r < 4; ++r) {
        int gr = row0 + ty * 4 + r;
        if (gr < n) {
            float4 v = make_float4(acc[r][0], acc[r][1], acc[r][2], acc[r][3]);
            *(float4*)&h1[(size_t)gr * 128 + tx * 4] = v;
        }
    }
}

// ---------------------------------------------------------------------------
// K1b: per-node attention terms  a_s1[n,h] = h1[n,h,:]·a_src1[h,:], same a_d1
// One wave (64 lanes) per node; lane owns 2 channels; reduce within 16-lane
// head groups.
// ---------------------------------------------------------------------------
__global__ __launch_bounds__(256) void k1b_attn(const float* __restrict__ h1,
                                                const float* __restrict__ a_src1,
                                                const float* __restrict__ a_dst1,
                                                float* __restrict__ a_s1,
                                                float* __restrict__ a_d1, int n) {
    int wid = (blockIdx.x * blockDim.x + threadIdx.x) >> 6;
    int lane = threadIdx.x & 63;
    if (wid >= n) return;
    int c0 = lane * 2;
    float2 h = *(const float2*)&h1[(size_t)wid * 128 + c0];
    float2 as = *(const float2*)&a_src1[c0];
    float2 ad = *(const float2*)&a_dst1[c0];
    float ps = h.x * as.x + h.y * as.y;
    float pd = h.x * ad.x + h.y * ad.y;
#pragma unroll
    for (int off = 1; off < 16; off <<= 1) {
        ps += __shfl_xor(ps, off);
        pd += __shfl_xor(pd, off);
    }
    if ((lane & 15) == 0) {
        int hd = lane >> 4;
        a_s1[wid * 4 + hd] = ps;
        a_d1[wid * 4 + hd] = pd;
    }
}

// ---------------------------------------------------------------------------
// CSR build: histogram -> scan (3 kernels) -> scatter
// ---------------------------------------------------------------------------
__global__ void k2_hist(const int* __restrict__ dst, int e, int* __restrict__ counts) {
    int i = blockIdx.x * blockDim.x + threadIdx.x;
    if (i < e) atomicAdd(&counts[dst[i]], 1);
}

__global__ __launch_bounds__(256) void k_scan1(const int* __restrict__ counts, int n,
                                               int* __restrict__ incl, int* __restrict__ bsums) {
    __shared__ int s[256];
    int tid = threadIdx.x;
    int g = blockIdx.x * 256 + tid;
    int v = (g < n) ? counts[g] : 0;
    s[tid] = v;
    __syncthreads();
    for (int off = 1; off < 256; off <<= 1) {
        int t = (tid >= off) ? s[tid - off] : 0;
        __syncthreads();
        s[tid] += t;
        __syncthreads();
    }
    if (g < n) incl[g] = s[tid];
    if (tid == 255) bsums[blockIdx.x] = s[255];
}

__global__ __launch_bounds__(256) void k_scan2(int* __restrict__ bsums, int nb) {
    __shared__ int s[256];
    int tid = threadIdx.x;
    int v = (tid < nb) ? bsums[tid] : 0;
    s[tid] = v;
    __syncthreads();
    for (int off = 1; off < 256; off <<= 1) {
        int t = (tid >= off) ? s[tid - off] : 0;
        __syncthreads();
        s[tid] += t;
        __syncthreads();
    }
    if (tid < nb) bsums[tid] = s[tid] - v;   // exclusive block offsets
}

__global__ void k_scan3(const int* __restrict__ incl, const int* __restrict__ boff,
                        int n, int* __restrict__ row_start) {
    int g = blockIdx.x * 256 + threadIdx.x;
    if (g < n) row_start[g + 1] = incl[g] + boff[blockIdx.x];
    if (g == 0) row_start[0] = 0;
}

__global__ void k2_scatter(const int* __restrict__ srcs, const int* __restrict__ dsts, int e,
                           const int* __restrict__ row_start, int* __restrict__ cursor,
                           int* __restrict__ csr_src) {
    int i = blockIdx.x * blockDim.x + threadIdx.x;
    if (i < e) {
        int d = dsts[i];
        int pos = atomicAdd(&cursor[d], 1);
        csr_src[row_start[d] + pos] = srcs[i];
    }
}

// ---------------------------------------------------------------------------
// K3: layer-1 softmax-aggregation (one wave per dst node) fused with
// relu + layer-2 projection (h2 = relu(out)@W2) + layer-2 attn dots.
// Lane owns channels {2l, 2l+1}; head = lane>>4 (16 lanes per head).
// Self-loop handled implicitly.
// ---------------------------------------------------------------------------
__global__ __launch_bounds__(256) void k3_agg1(
    const float* __restrict__ h1, const float* __restrict__ a_s1,
    const float* __restrict__ a_d1, const int* __restrict__ row_start,
    const int* __restrict__ csr_src, const float* __restrict__ b1,
    const float* __restrict__ W2, const float* __restrict__ a_src2,
    const float* __restrict__ a_dst2, float* __restrict__ h2,
    float* __restrict__ a_s2, float* __restrict__ a_d2, int n) {
    int wid = (blockIdx.x * blockDim.x + threadIdx.x) >> 6;
    int lane = threadIdx.x & 63;
    if (wid >= n) return;
    const int hd = lane >> 4;
    const int c0 = lane * 2;
    const int rs = row_start[wid];
    const int deg = row_start[wid + 1] - rs;
    const float ad = a_d1[wid * 4 + hd];
    const float e_self = lrelu(a_s1[wid * 4 + hd] + ad);

    // --- phase 1: per-head max over incoming edges (+self-loop)
    float mx = e_self;
    for (int j = (lane & 15); j < deg; j += 16) {
        int s = csr_src[rs + j];
        mx = fmaxf(mx, lrelu(a_s1[s * 4 + hd] + ad));
    }
#pragma unroll
    for (int off = 1; off < 16; off <<= 1) mx = fmaxf(mx, __shfl_xor(mx, off));

    // --- phase 2: accumulate numerator and denominator (whole wave per edge)
    float acc0 = 0.f, acc1 = 0.f, denom = 0.f;
    int j = 0;
    for (; j + 2 <= deg; j += 2) {
        int s0 = csr_src[rs + j];
        int s1 = csr_src[rs + j + 1];
        float e0 = lrelu(a_s1[s0 * 4 + hd] + ad);
        float e1 = lrelu(a_s1[s1 * 4 + hd] + ad);
        float2 hv0 = *(const float2*)&h1[(size_t)s0 * 128 + c0];
        float2 hv1 = *(const float2*)&h1[(size_t)s1 * 128 + c0];
        float p0 = __expf(e0 - mx);
        float p1 = __expf(e1 - mx);
        denom += p0 + p1;
        acc0 += p0 * hv0.x + p1 * hv1.x;
        acc1 += p0 * hv0.y + p1 * hv1.y;
    }
    if (j < deg) {
        int s0 = csr_src[rs + j];
        float e0 = lrelu(a_s1[s0 * 4 + hd] + ad);
        float2 hv0 = *(const float2*)&h1[(size_t)s0 * 128 + c0];
        float p0 = __expf(e0 - mx);
        denom += p0;
        acc0 += p0 * hv0.x;
        acc1 += p0 * hv0.y;
    }
    {   // self-loop
        float p = __expf(e_self - mx);
        float2 hv = *(const float2*)&h1[(size_t)wid * 128 + c0];
        denom += p;
        acc0 += p * hv.x;
        acc1 += p * hv.y;
    }
    float inv = 1.f / (denom + 1e-16f);
    float2 bv = *(const float2*)&b1[c0];
    float r0 = fmaxf(acc0 * inv + bv.x, 0.f);   // +bias, relu
    float r1 = fmaxf(acc1 * inv + bv.y, 0.f);

    // --- fused layer-2 projection: h2[wid][k] = sum_c relu_out[c]*W2[c][k]
    float4 w = *(const float4*)&W2[c0 * 2];     // W2[c0][0..1], W2[c0+1][0..1]
    float p0 = r0 * w.x + r1 * w.z;
    float p1 = r0 * w.y + r1 * w.w;
#pragma unroll
    for (int off = 1; off < 64; off <<= 1) {
        p0 += __shfl_xor(p0, off);
        p1 += __shfl_xor(p1, off);
    }
    if (lane == 0) {
        h2[wid * 2 + 0] = p0;
        h2[wid * 2 + 1] = p1;
        a_s2[wid] = p0 * a_src2[0] + p1 * a_src2[1];
        a_d2[wid] = p0 * a_dst2[0] + p1 * a_dst2[1];
    }
}

// ---------------------------------------------------------------------------
// K4: layer-2 softmax-aggregation (1 head, 2 channels) + bias + log_softmax.
// One wave per node; lanes stride over edges; full-wave reductions.
// ---------------------------------------------------------------------------
__global__ __launch_bounds__(256) void k4_agg2(
    const float* __restrict__ h2, const float* __restrict__ a_s2,
    const float* __restrict__ a_d2, const int* __restrict__ row_start,
    const int* __restrict__ csr_src, const float* __restrict__ b2,
    float* __restrict__ out, int n) {
    int wid = (blockIdx.x * blockDim.x + threadIdx.x) >> 6;
    int lane = threadIdx.x & 63;
    if (wid >= n) return;
    const int rs = row_start[wid];
    const int deg = row_start[wid + 1] - rs;
    const float ad = a_d2[wid];
    const float e_self = lrelu(a_s2[wid] + ad);

    float mx = e_self;
    for (int j = lane; j < deg; j += 64) {
        int s = csr_src[rs + j];
        mx = fmaxf(mx, lrelu(a_s2[s] + ad));
    }
#pragma unroll
    for (int off = 1; off < 64; off <<= 1) mx = fmaxf(mx, __shfl_xor(mx, off));

    float dnm = 0.f, a0 = 0.f, a1 = 0.f;
    for (int j = lane; j < deg; j += 64) {
        int s = csr_src[rs + j];
        float p = __expf(lrelu(a_s2[s] + ad) - mx);
        float2 hv = *(const float2*)&h2[(size_t)s * 2];
        dnm += p;
        a0 += p * hv.x;
        a1 += p * hv.y;
    }
    if (lane == 0) {   // self-loop
        float p = __expf(e_self - mx);
        float2 hv = *(const float2*)&h2[(size_t)wid * 2];
        dnm += p;
        a0 += p * hv.x;
        a1 += p * hv.y;
    }
#pragma unroll
    for (int off = 1; off < 64; off <<= 1) {
        dnm += __shfl_xor(dnm, off);
        a0 += __shfl_xor(a0, off);
        a1 += __shfl_xor(a1, off);
    }
    if (lane == 0) {
        float inv = 1.f / (dnm + 1e-16f);
        float o0 = a0 * inv + b2[0];
        float o1 = a1 * inv + b2[1];
        float m2 = fmaxf(o0, o1);
        float lse = m2 + logf(__expf(o0 - m2) + __expf(o1 - m2));
        out[wid * 2 + 0] = o0 - lse;
        out[wid * 2 + 1] = o1 - lse;
    }
}

// ---------------------------------------------------------------------------
extern "C" void kernel_launch(void* const* d_in, const int* in_sizes, int n_in,
                              void* d_out, int out_size, void* d_ws, size_t ws_size,
                              hipStream_t stream) {
    const float* x      = (const float*)d_in[0];
    const int*   ei     = (const int*)d_in[1];
    const float* W1     = (const float*)d_in[2];
    const float* a_src1 = (const float*)d_in[3];
    const float* a_dst1 = (const float*)d_in[4];
    const float* b1     = (const float*)d_in[5];
    const float* W2     = (const float*)d_in[6];
    const float* a_src2 = (const float*)d_in[7];
    const float* a_dst2 = (const float*)d_in[8];
    const float* b2     = (const float*)d_in[9];
    float* out = (float*)d_out;

    const int N = in_sizes[0] / 128;
    const int E = in_sizes[1] / 2;
    const int* e_src = ei;        // edge_index[0]
    const int* e_dst = ei + E;    // edge_index[1]

    // ---- workspace carve (aligned 256B)
    char* p = (char*)d_ws;
    auto alloc = [&](size_t bytes) -> void* {
        void* r = (void*)p;
        p += (bytes + 255) & ~(size_t)255;
        return r;
    };
    float* h1        = (float*)alloc((size_t)N * 128 * 4);
    float* a_s1      = (float*)alloc((size_t)N * 4 * 4);
    float* a_d1      = (float*)alloc((size_t)N * 4 * 4);
    float* h2        = (float*)alloc((size_t)N * 2 * 4);
    float* a_s2      = (float*)alloc((size_t)N * 4);
    float* a_d2      = (float*)alloc((size_t)N * 4);
    int*   counts    = (int*)alloc((size_t)2 * N * 4);   // counts + cursor contiguous
    int*   cursor    = counts + N;
    int*   incl      = (int*)alloc((size_t)N * 4);
    int*   bsums     = (int*)alloc(256 * 4);
    int*   row_start = (int*)alloc((size_t)(N + 1) * 4);
    int*   csr_src   = (int*)alloc((size_t)E * 4);

    // zero counts + cursor in one memset
    hipMemsetAsync(counts, 0, (size_t)2 * N * 4, stream);

    const int NB = (N + 255) / 256;          // scan blocks (196)

    k1_gemm<<<(N + 31) / 32, 256, 0, stream>>>(x, W1, h1, N);
    k1b_attn<<<(N * 64 + 255) / 256, 256, 0, stream>>>(h1, a_src1, a_dst1, a_s1, a_d1, N);

    k2_hist<<<(E + 255) / 256, 256, 0, stream>>>(e_dst, E, counts);
    k_scan1<<<NB, 256, 0, stream>>>(counts, N, incl, bsums);
    k_scan2<<<1, 256, 0, stream>>>(bsums, NB);
    k_scan3<<<NB, 256, 0, stream>>>(incl, bsums, N, row_start);
    k2_scatter<<<(E + 255) / 256, 256, 0, stream>>>(e_src, e_dst, E, row_start, cursor, csr_src);

    k3_agg1<<<(N * 64 + 255) / 256, 256, 0, stream>>>(h1, a_s1, a_d1, row_start, csr_src,
                                                      b1, W2, a_src2, a_dst2,
                                                      h2, a_s2, a_d2, N);
    k4_agg2<<<(N * 64 + 255) / 256, 256, 0, stream>>>(h2, a_s2, a_d2, row_start, csr_src,
                                                      b2, out, N);
}

// Round 2
// 273.312 us; speedup vs baseline: 1.1431x; 1.1431x over previous
//
#include <hip/hip_runtime.h>
#include <hip/hip_bf16.h>

#define NEG_SLOPE 0.2f

__device__ __forceinline__ float lrelu(float v) {
    return v > 0.f ? v : NEG_SLOPE * v;
}

// ---------------------------------------------------------------------------
// K1: h1[N,128] = x[N,128] @ W1[128,128]  (fp32 vector GEMM)
// + fused epilogue computing a_s1[n,h] = h1[n,h,:]·a_src1[h,:] and a_d1.
// Tile: 32 rows x 128 cols per block of 256 threads; 4x4 register blocking.
// ---------------------------------------------------------------------------
__global__ __launch_bounds__(256) void k1_gemm(const float* __restrict__ x,
                                               const float* __restrict__ W1,
                                               const float* __restrict__ a_src1,
                                               const float* __restrict__ a_dst1,
                                               float* __restrict__ h1,
                                               float* __restrict__ a_s1,
                                               float* __restrict__ a_d1, int n) {
    __shared__ float xs[32][128];
    const int tid = threadIdx.x;
    const int row0 = blockIdx.x * 32;
    for (int i = 0; i < 4; ++i) {
        int f4 = tid + i * 256;          // 0..1023
        int r = f4 >> 5;
        int c = (f4 & 31) * 4;
        int gr = row0 + r;
        float4 v = make_float4(0.f, 0.f, 0.f, 0.f);
        if (gr < n) v = *(const float4*)&x[(size_t)gr * 128 + c];
        *(float4*)&xs[r][c] = v;
    }
    __syncthreads();
    const int tx = tid & 31;             // cols 4*tx..4*tx+3
    const int ty = tid >> 5;             // rows 4*ty..4*ty+3
    float acc[4][4] = {};
#pragma unroll 4
    for (int k = 0; k < 128; ++k) {
        float4 wv = *(const float4*)&W1[k * 128 + tx * 4];
        float xv[4];
#pragma unroll
        for (int r = 0; r < 4; ++r) xv[r] = xs[ty * 4 + r][k];
#pragma unroll
        for (int r = 0; r < 4; ++r) {
            acc[r][0] += xv[r] * wv.x;
            acc[r][1] += xv[r] * wv.y;
            acc[r][2] += xv[r] * wv.z;
            acc[r][3] += xv[r] * wv.w;
        }
    }
#pragma unroll
    for (int r = 0; r < 4; ++r) {
        int gr = row0 + ty * 4 + r;
        if (gr < n) {
            float4 v = make_float4(acc[r][0], acc[r][1], acc[r][2], acc[r][3]);
            *(float4*)&h1[(size_t)gr * 128 + tx * 4] = v;
        }
    }
    // --- fused attention-dot epilogue ---
    float4 asv = *(const float4*)&a_src1[tx * 4];
    float4 adv = *(const float4*)&a_dst1[tx * 4];
    float ps[4], pd[4];
#pragma unroll
    for (int r = 0; r < 4; ++r) {
        ps[r] = acc[r][0] * asv.x + acc[r][1] * asv.y + acc[r][2] * asv.z + acc[r][3] * asv.w;
        pd[r] = acc[r][0] * adv.x + acc[r][1] * adv.y + acc[r][2] * adv.z + acc[r][3] * adv.w;
    }
#pragma unroll
    for (int off = 1; off < 8; off <<= 1) {
#pragma unroll
        for (int r = 0; r < 4; ++r) {
            ps[r] += __shfl_xor(ps[r], off);
            pd[r] += __shfl_xor(pd[r], off);
        }
    }
    if ((tx & 7) == 0) {
        int hd = tx >> 3;
#pragma unroll
        for (int r = 0; r < 4; ++r) {
            int gr = row0 + ty * 4 + r;
            if (gr < n) {
                a_s1[gr * 4 + hd] = ps[r];
                a_d1[gr * 4 + hd] = pd[r];
            }
        }
    }
}

// ---------------------------------------------------------------------------
// CSR build: histogram -> scan (3 kernels) -> scatter
// ---------------------------------------------------------------------------
__global__ void k2_hist(const int* __restrict__ dst, int e, int* __restrict__ counts) {
    int i = blockIdx.x * blockDim.x + threadIdx.x;
    if (i < e) atomicAdd(&counts[dst[i]], 1);
}

__global__ __launch_bounds__(256) void k_scan1(const int* __restrict__ counts, int n,
                                               int* __restrict__ incl, int* __restrict__ bsums) {
    __shared__ int s[256];
    int tid = threadIdx.x;
    int g = blockIdx.x * 256 + tid;
    int v = (g < n) ? counts[g] : 0;
    s[tid] = v;
    __syncthreads();
    for (int off = 1; off < 256; off <<= 1) {
        int t = (tid >= off) ? s[tid - off] : 0;
        __syncthreads();
        s[tid] += t;
        __syncthreads();
    }
    if (g < n) incl[g] = s[tid];
    if (tid == 255) bsums[blockIdx.x] = s[255];
}

__global__ __launch_bounds__(256) void k_scan2(int* __restrict__ bsums, int nb) {
    __shared__ int s[256];
    int tid = threadIdx.x;
    int v = (tid < nb) ? bsums[tid] : 0;
    s[tid] = v;
    __syncthreads();
    for (int off = 1; off < 256; off <<= 1) {
        int t = (tid >= off) ? s[tid - off] : 0;
        __syncthreads();
        s[tid] += t;
        __syncthreads();
    }
    if (tid < nb) bsums[tid] = s[tid] - v;   // exclusive block offsets
}

// row_start[g+1] = inclusive scan; cursor[g] = exclusive scan (scatter cursor seed)
__global__ void k_scan3(const int* __restrict__ incl, const int* __restrict__ boff,
                        const int* __restrict__ counts, int n,
                        int* __restrict__ row_start, int* __restrict__ cursor) {
    int g = blockIdx.x * 256 + threadIdx.x;
    if (g < n) {
        int v = incl[g] + boff[blockIdx.x];
        row_start[g + 1] = v;
        cursor[g] = v - counts[g];
    }
    if (g == 0) row_start[0] = 0;
}

__global__ void k2_scatter(const int* __restrict__ srcs, const int* __restrict__ dsts, int e,
                           int* __restrict__ cursor, int* __restrict__ csr_src) {
    int i = blockIdx.x * blockDim.x + threadIdx.x;
    if (i < e) {
        int pos = atomicAdd(&cursor[dsts[i]], 1);
        csr_src[pos] = srcs[i];
    }
}

// ---------------------------------------------------------------------------
// K3: layer-1 softmax-aggregation, single pass (no max shift — logits are
// bounded, exp is exact-safe in fp32, alpha = p/Σp is shift-invariant).
// One wave per dst node; half-wave per edge: lanes 0-31 take even edges,
// 32-63 odd edges; each lane owns 4 channels (float4 gather = 16B/lane).
// Fused: +bias, relu, layer-2 projection, layer-2 attention dots ->
// pk[node] = (h2_0, h2_1, a_s2, a_d2).
// ---------------------------------------------------------------------------
__global__ __launch_bounds__(256) void k3_agg1(
    const float* __restrict__ h1g, const float* __restrict__ a_s1,
    const float* __restrict__ a_d1, const int* __restrict__ row_start,
    const int* __restrict__ csr_src, const float* __restrict__ b1,
    const float* __restrict__ W2, const float* __restrict__ a_src2,
    const float* __restrict__ a_dst2, float4* __restrict__ pk, int n) {
    const int wid = (blockIdx.x * blockDim.x + threadIdx.x) >> 6;
    const int lane = threadIdx.x & 63;
    if (wid >= n) return;
    const int half = lane >> 5;          // 0: even edges, 1: odd edges
    const int l5 = lane & 31;
    const int c0 = l5 * 4;               // 4 channels per lane
    const int head = l5 >> 3;
    const int rs = row_start[wid];
    const int deg = row_start[wid + 1] - rs;
    const float ad = a_d1[wid * 4 + head];

    float dnm = 0.f;
    float acc0 = 0.f, acc1 = 0.f, acc2 = 0.f, acc3 = 0.f;
    int j = half;
    for (; j + 2 < deg; j += 4) {        // 2 edges per half-wave per iter
        int s0 = csr_src[rs + j];
        int s1 = csr_src[rs + j + 2];
        float as0 = a_s1[s0 * 4 + head];
        float as1 = a_s1[s1 * 4 + head];
        float4 hv0 = *(const float4*)&h1g[(size_t)s0 * 128 + c0];
        float4 hv1 = *(const float4*)&h1g[(size_t)s1 * 128 + c0];
        float p0 = __expf(lrelu(as0 + ad));
        float p1 = __expf(lrelu(as1 + ad));
        dnm += p0 + p1;
        acc0 += p0 * hv0.x + p1 * hv1.x;
        acc1 += p0 * hv0.y + p1 * hv1.y;
        acc2 += p0 * hv0.z + p1 * hv1.z;
        acc3 += p0 * hv0.w + p1 * hv1.w;
    }
    if (j < deg) {
        int s0 = csr_src[rs + j];
        float as0 = a_s1[s0 * 4 + head];
        float4 hv0 = *(const float4*)&h1g[(size_t)s0 * 128 + c0];
        float p0 = __expf(lrelu(as0 + ad));
        dnm += p0;
        acc0 += p0 * hv0.x;
        acc1 += p0 * hv0.y;
        acc2 += p0 * hv0.z;
        acc3 += p0 * hv0.w;
    }
    // combine even/odd halves (lane l and l^32 hold same head/channels)
    dnm += __shfl_xor(dnm, 32);
    acc0 += __shfl_xor(acc0, 32);
    acc1 += __shfl_xor(acc1, 32);
    acc2 += __shfl_xor(acc2, 32);
    acc3 += __shfl_xor(acc3, 32);
    // self-loop (identical in all lanes post-combine)
    {
        float p = __expf(lrelu(a_s1[wid * 4 + head] + ad));
        float4 hv = *(const float4*)&h1g[(size_t)wid * 128 + c0];
        dnm += p;
        acc0 += p * hv.x;
        acc1 += p * hv.y;
        acc2 += p * hv.z;
        acc3 += p * hv.w;
    }
    float inv = 1.f / (dnm + 1e-16f);
    float4 bv = *(const float4*)&b1[c0];
    float r0 = fmaxf(acc0 * inv + bv.x, 0.f);
    float r1 = fmaxf(acc1 * inv + bv.y, 0.f);
    float r2 = fmaxf(acc2 * inv + bv.z, 0.f);
    float r3 = fmaxf(acc3 * inv + bv.w, 0.f);

    // fused layer-2 projection: h2[k] = sum_c relu_out[c] * W2[c][k]
    float4 w01 = *(const float4*)&W2[c0 * 2];       // W2[c0][0:2], W2[c0+1][0:2]
    float4 w23 = *(const float4*)&W2[c0 * 2 + 4];   // W2[c0+2][0:2], W2[c0+3][0:2]
    float p0 = r0 * w01.x + r1 * w01.z + r2 * w23.x + r3 * w23.z;
    float p1 = r0 * w01.y + r1 * w01.w + r2 * w23.y + r3 * w23.w;
#pragma unroll
    for (int off = 1; off < 32; off <<= 1) {
        p0 += __shfl_xor(p0, off);
        p1 += __shfl_xor(p1, off);
    }
    if (lane == 0) {
        pk[wid] = make_float4(p0, p1,
                              p0 * a_src2[0] + p1 * a_src2[1],
                              p0 * a_dst2[0] + p1 * a_dst2[1]);
    }
}

// ---------------------------------------------------------------------------
// K4: layer-2 softmax-aggregation (1 head, 2 ch) + bias + log_softmax.
// 16 lanes per node (4 nodes per wave); single pass, no max shift.
// pk[s] = (h2_0, h2_1, a_s2, a_d2) -> one 16B gather per edge.
// ---------------------------------------------------------------------------
__global__ __launch_bounds__(256) void k4_agg2(
    const float4* __restrict__ pk, const int* __restrict__ row_start,
    const int* __restrict__ csr_src, const float* __restrict__ b2,
    float* __restrict__ out, int n) {
    const int g = blockIdx.x * blockDim.x + threadIdx.x;
    const int lane = threadIdx.x & 63;
    const int node = (g >> 6) * 4 + (lane >> 4);
    const int l16 = lane & 15;
    if (node >= n) return;
    const int rs = row_start[node];
    const int deg = row_start[node + 1] - rs;
    const float4 me = pk[node];
    const float ad = me.w;

    float dnm = 0.f, a0 = 0.f, a1 = 0.f;
    for (int j = l16; j < deg; j += 16) {
        int s = csr_src[rs + j];
        float4 q = pk[s];
        float p = __expf(lrelu(q.z + ad));
        dnm += p;
        a0 += p * q.x;
        a1 += p * q.y;
    }
    if (l16 == 0) {   // self-loop
        float p = __expf(lrelu(me.z + ad));
        dnm += p;
        a0 += p * me.x;
        a1 += p * me.y;
    }
#pragma unroll
    for (int off = 1; off < 16; off <<= 1) {
        dnm += __shfl_xor(dnm, off);
        a0 += __shfl_xor(a0, off);
        a1 += __shfl_xor(a1, off);
    }
    if (l16 == 0) {
        float inv = 1.f / (dnm + 1e-16f);
        float o0 = a0 * inv + b2[0];
        float o1 = a1 * inv + b2[1];
        float m2 = fmaxf(o0, o1);
        float lse = m2 + logf(__expf(o0 - m2) + __expf(o1 - m2));
        out[node * 2 + 0] = o0 - lse;
        out[node * 2 + 1] = o1 - lse;
    }
}

// ---------------------------------------------------------------------------
extern "C" void kernel_launch(void* const* d_in, const int* in_sizes, int n_in,
                              void* d_out, int out_size, void* d_ws, size_t ws_size,
                              hipStream_t stream) {
    const float* x      = (const float*)d_in[0];
    const int*   ei     = (const int*)d_in[1];
    const float* W1     = (const float*)d_in[2];
    const float* a_src1 = (const float*)d_in[3];
    const float* a_dst1 = (const float*)d_in[4];
    const float* b1     = (const float*)d_in[5];
    const float* W2     = (const float*)d_in[6];
    const float* a_src2 = (const float*)d_in[7];
    const float* a_dst2 = (const float*)d_in[8];
    const float* b2     = (const float*)d_in[9];
    float* out = (float*)d_out;

    const int N = in_sizes[0] / 128;
    const int E = in_sizes[1] / 2;
    const int* e_src = ei;        // edge_index[0]
    const int* e_dst = ei + E;    // edge_index[1]

    // ---- workspace carve (256B aligned)
    char* p = (char*)d_ws;
    auto alloc = [&](size_t bytes) -> void* {
        void* r = (void*)p;
        p += (bytes + 255) & ~(size_t)255;
        return r;
    };
    float*  h1        = (float*)alloc((size_t)N * 128 * 4);
    float*  a_s1      = (float*)alloc((size_t)N * 4 * 4);
    float*  a_d1      = (float*)alloc((size_t)N * 4 * 4);
    float4* pk        = (float4*)alloc((size_t)N * 16);
    int*    counts    = (int*)alloc((size_t)N * 4);
    int*    cursor    = (int*)alloc((size_t)N * 4);
    int*    incl      = (int*)alloc((size_t)N * 4);
    int*    bsums     = (int*)alloc(256 * 4);
    int*    row_start = (int*)alloc((size_t)(N + 1) * 4);
    int*    csr_src   = (int*)alloc((size_t)E * 4);

    hipMemsetAsync(counts, 0, (size_t)N * 4, stream);

    const int NB = (N + 255) / 256;

    k1_gemm<<<(N + 31) / 32, 256, 0, stream>>>(x, W1, a_src1, a_dst1, h1, a_s1, a_d1, N);

    k2_hist<<<(E + 255) / 256, 256, 0, stream>>>(e_dst, E, counts);
    k_scan1<<<NB, 256, 0, stream>>>(counts, N, incl, bsums);
    k_scan2<<<1, 256, 0, stream>>>(bsums, NB);
    k_scan3<<<NB, 256, 0, stream>>>(incl, bsums, counts, N, row_start, cursor);
    k2_scatter<<<(E + 255) / 256, 256, 0, stream>>>(e_src, e_dst, E, cursor, csr_src);

    k3_agg1<<<(N * 64 + 255) / 256, 256, 0, stream>>>(h1, a_s1, a_d1, row_start, csr_src,
                                                      b1, W2, a_src2, a_dst2, pk, N);
    k4_agg2<<<((N + 3) / 4 * 64 + 255) / 256, 256, 0, stream>>>(pk, row_start, csr_src,
                                                                b2, out, N);
}

// Round 3
// 251.567 us; speedup vs baseline: 1.2419x; 1.0864x over previous
//
#include <hip/hip_runtime.h>
#include <hip/hip_bf16.h>

#define NEG_SLOPE 0.2f

__device__ __forceinline__ float lrelu(float v) {
    return v > 0.f ? v : NEG_SLOPE * v;
}

__device__ __forceinline__ unsigned short f2bf(float f) {   // RNE float->bf16
    unsigned int u = __float_as_uint(f);
    u = (u + 0x7fffu + ((u >> 16) & 1u)) >> 16;
    return (unsigned short)u;
}

__device__ __forceinline__ float2 bfpair(unsigned int u) {  // 2 packed bf16 -> 2 floats
    float2 r;
    r.x = __uint_as_float(u << 16);
    r.y = __uint_as_float(u & 0xffff0000u);
    return r;
}

// ---------------------------------------------------------------------------
// K1: h1b[N,128] (bf16) = x[N,128] @ W1[128,128]  (fp32 vector GEMM)
// + fused epilogue computing a_s1[n,h], a_d1[n,h] in fp32.
// Tile: 32 rows x 128 cols per block of 256 threads; 4x4 register blocking.
// ---------------------------------------------------------------------------
__global__ __launch_bounds__(256) void k1_gemm(const float* __restrict__ x,
                                               const float* __restrict__ W1,
                                               const float* __restrict__ a_src1,
                                               const float* __restrict__ a_dst1,
                                               unsigned short* __restrict__ h1b,
                                               float* __restrict__ a_s1,
                                               float* __restrict__ a_d1, int n) {
    __shared__ float xs[32][128];
    const int tid = threadIdx.x;
    const int row0 = blockIdx.x * 32;
    for (int i = 0; i < 4; ++i) {
        int f4 = tid + i * 256;          // 0..1023
        int r = f4 >> 5;
        int c = (f4 & 31) * 4;
        int gr = row0 + r;
        float4 v = make_float4(0.f, 0.f, 0.f, 0.f);
        if (gr < n) v = *(const float4*)&x[(size_t)gr * 128 + c];
        *(float4*)&xs[r][c] = v;
    }
    __syncthreads();
    const int tx = tid & 31;             // cols 4*tx..4*tx+3
    const int ty = tid >> 5;             // rows 4*ty..4*ty+3
    float acc[4][4] = {};
#pragma unroll 4
    for (int k = 0; k < 128; ++k) {
        float4 wv = *(const float4*)&W1[k * 128 + tx * 4];
        float xv[4];
#pragma unroll
        for (int r = 0; r < 4; ++r) xv[r] = xs[ty * 4 + r][k];
#pragma unroll
        for (int r = 0; r < 4; ++r) {
            acc[r][0] += xv[r] * wv.x;
            acc[r][1] += xv[r] * wv.y;
            acc[r][2] += xv[r] * wv.z;
            acc[r][3] += xv[r] * wv.w;
        }
    }
#pragma unroll
    for (int r = 0; r < 4; ++r) {
        int gr = row0 + ty * 4 + r;
        if (gr < n) {
            ushort4 v;
            v.x = f2bf(acc[r][0]);
            v.y = f2bf(acc[r][1]);
            v.z = f2bf(acc[r][2]);
            v.w = f2bf(acc[r][3]);
            *(ushort4*)&h1b[(size_t)gr * 128 + tx * 4] = v;
        }
    }
    // --- fused attention-dot epilogue (fp32) ---
    float4 asv = *(const float4*)&a_src1[tx * 4];
    float4 adv = *(const float4*)&a_dst1[tx * 4];
    float ps[4], pd[4];
#pragma unroll
    for (int r = 0; r < 4; ++r) {
        ps[r] = acc[r][0] * asv.x + acc[r][1] * asv.y + acc[r][2] * asv.z + acc[r][3] * asv.w;
        pd[r] = acc[r][0] * adv.x + acc[r][1] * adv.y + acc[r][2] * adv.z + acc[r][3] * adv.w;
    }
#pragma unroll
    for (int off = 1; off < 8; off <<= 1) {
#pragma unroll
        for (int r = 0; r < 4; ++r) {
            ps[r] += __shfl_xor(ps[r], off);
            pd[r] += __shfl_xor(pd[r], off);
        }
    }
    if ((tx & 7) == 0) {
        int hd = tx >> 3;
#pragma unroll
        for (int r = 0; r < 4; ++r) {
            int gr = row0 + ty * 4 + r;
            if (gr < n) {
                a_s1[gr * 4 + hd] = ps[r];
                a_d1[gr * 4 + hd] = pd[r];
            }
        }
    }
}

// ---------------------------------------------------------------------------
// CSR build: histogram -> scan (3 kernels) -> scatter
// ---------------------------------------------------------------------------
__global__ void k2_hist(const int* __restrict__ dst, int e, int* __restrict__ counts) {
    int i = blockIdx.x * blockDim.x + threadIdx.x;
    if (i < e) atomicAdd(&counts[dst[i]], 1);
}

__global__ __launch_bounds__(256) void k_scan1(const int* __restrict__ counts, int n,
                                               int* __restrict__ incl, int* __restrict__ bsums) {
    __shared__ int s[256];
    int tid = threadIdx.x;
    int g = blockIdx.x * 256 + tid;
    int v = (g < n) ? counts[g] : 0;
    s[tid] = v;
    __syncthreads();
    for (int off = 1; off < 256; off <<= 1) {
        int t = (tid >= off) ? s[tid - off] : 0;
        __syncthreads();
        s[tid] += t;
        __syncthreads();
    }
    if (g < n) incl[g] = s[tid];
    if (tid == 255) bsums[blockIdx.x] = s[255];
}

__global__ __launch_bounds__(256) void k_scan2(int* __restrict__ bsums, int nb) {
    __shared__ int s[256];
    int tid = threadIdx.x;
    int v = (tid < nb) ? bsums[tid] : 0;
    s[tid] = v;
    __syncthreads();
    for (int off = 1; off < 256; off <<= 1) {
        int t = (tid >= off) ? s[tid - off] : 0;
        __syncthreads();
        s[tid] += t;
        __syncthreads();
    }
    if (tid < nb) bsums[tid] = s[tid] - v;   // exclusive block offsets
}

// row_start[g+1] = inclusive scan; cursor[g] = exclusive scan (scatter cursor seed)
__global__ void k_scan3(const int* __restrict__ incl, const int* __restrict__ boff,
                        const int* __restrict__ counts, int n,
                        int* __restrict__ row_start, int* __restrict__ cursor) {
    int g = blockIdx.x * 256 + threadIdx.x;
    if (g < n) {
        int v = incl[g] + boff[blockIdx.x];
        row_start[g + 1] = v;
        cursor[g] = v - counts[g];
    }
    if (g == 0) row_start[0] = 0;
}

__global__ void k2_scatter(const int* __restrict__ srcs, const int* __restrict__ dsts, int e,
                           int* __restrict__ cursor, int* __restrict__ csr_src) {
    int i = blockIdx.x * blockDim.x + threadIdx.x;
    if (i < e) {
        int pos = atomicAdd(&cursor[dsts[i]], 1);
        csr_src[pos] = srcs[i];
    }
}

// ---------------------------------------------------------------------------
// K3: layer-1 softmax-aggregation, single pass (no max shift — logits bounded,
// alpha = p/Σp is shift-invariant).
// One wave per dst node; QUARTER-wave per edge (4 edges in flight, unroll 2
// -> 8 independent gather chains). Lane owns 8 channels (16B bf16 gather).
// Fused: +bias, relu, layer-2 projection, layer-2 attn dots ->
// pk[node] = (h2_0, h2_1, a_s2, a_d2).
// ---------------------------------------------------------------------------
__global__ __launch_bounds__(256) void k3_agg1(
    const unsigned short* __restrict__ h1b, const float* __restrict__ a_s1,
    const float* __restrict__ a_d1, const int* __restrict__ row_start,
    const int* __restrict__ csr_src, const float* __restrict__ b1,
    const float* __restrict__ W2, const float* __restrict__ a_src2,
    const float* __restrict__ a_dst2, float4* __restrict__ pk, int n) {
    const int wid = (blockIdx.x * blockDim.x + threadIdx.x) >> 6;
    const int lane = threadIdx.x & 63;
    if (wid >= n) return;
    const int q = lane >> 4;             // quarter: edge slot 0..3
    const int l16 = lane & 15;
    const int c0 = l16 * 8;              // 8 channels per lane
    const int head = l16 >> 2;           // 4 lanes per head (32 ch/head)
    const int rs = row_start[wid];
    const int deg = row_start[wid + 1] - rs;
    const float ad = a_d1[wid * 4 + head];

    float dnm = 0.f;
    float acc[8] = {};
    int j = q;
    for (; j + 4 < deg; j += 8) {        // 2 edges per quarter per iter
        int s0 = csr_src[rs + j];
        int s1 = csr_src[rs + j + 4];
        float as0 = a_s1[s0 * 4 + head];
        float as1 = a_s1[s1 * 4 + head];
        uint4 g0 = *(const uint4*)&h1b[(size_t)s0 * 128 + c0];
        uint4 g1 = *(const uint4*)&h1b[(size_t)s1 * 128 + c0];
        float p0 = __expf(lrelu(as0 + ad));
        float p1 = __expf(lrelu(as1 + ad));
        dnm += p0 + p1;
        float2 h0a = bfpair(g0.x), h0b = bfpair(g0.y), h0c = bfpair(g0.z), h0d = bfpair(g0.w);
        float2 h1a = bfpair(g1.x), h1b2 = bfpair(g1.y), h1c = bfpair(g1.z), h1d = bfpair(g1.w);
        acc[0] += p0 * h0a.x + p1 * h1a.x;  acc[1] += p0 * h0a.y + p1 * h1a.y;
        acc[2] += p0 * h0b.x + p1 * h1b2.x; acc[3] += p0 * h0b.y + p1 * h1b2.y;
        acc[4] += p0 * h0c.x + p1 * h1c.x;  acc[5] += p0 * h0c.y + p1 * h1c.y;
        acc[6] += p0 * h0d.x + p1 * h1d.x;  acc[7] += p0 * h0d.y + p1 * h1d.y;
    }
    if (j < deg) {
        int s0 = csr_src[rs + j];
        float as0 = a_s1[s0 * 4 + head];
        uint4 g0 = *(const uint4*)&h1b[(size_t)s0 * 128 + c0];
        float p0 = __expf(lrelu(as0 + ad));
        dnm += p0;
        float2 ha = bfpair(g0.x), hb = bfpair(g0.y), hc = bfpair(g0.z), hd2 = bfpair(g0.w);
        acc[0] += p0 * ha.x;  acc[1] += p0 * ha.y;
        acc[2] += p0 * hb.x;  acc[3] += p0 * hb.y;
        acc[4] += p0 * hc.x;  acc[5] += p0 * hc.y;
        acc[6] += p0 * hd2.x; acc[7] += p0 * hd2.y;
    }
    // combine quarters (lanes l16, l16+16, l16+32, l16+48 share channels/head)
    dnm += __shfl_xor(dnm, 16);
    dnm += __shfl_xor(dnm, 32);
#pragma unroll
    for (int k = 0; k < 8; ++k) {
        acc[k] += __shfl_xor(acc[k], 16);
        acc[k] += __shfl_xor(acc[k], 32);
    }
    // self-loop (identical across quarters — redundant but uniform)
    {
        float p = __expf(lrelu(a_s1[wid * 4 + head] + ad));
        uint4 g0 = *(const uint4*)&h1b[(size_t)wid * 128 + c0];
        float2 ha = bfpair(g0.x), hb = bfpair(g0.y), hc = bfpair(g0.z), hd2 = bfpair(g0.w);
        dnm += p;
        acc[0] += p * ha.x;  acc[1] += p * ha.y;
        acc[2] += p * hb.x;  acc[3] += p * hb.y;
        acc[4] += p * hc.x;  acc[5] += p * hc.y;
        acc[6] += p * hd2.x; acc[7] += p * hd2.y;
    }
    float inv = 1.f / (dnm + 1e-16f);
    float r[8];
    float4 bva = *(const float4*)&b1[c0];
    float4 bvb = *(const float4*)&b1[c0 + 4];
    r[0] = fmaxf(acc[0] * inv + bva.x, 0.f);
    r[1] = fmaxf(acc[1] * inv + bva.y, 0.f);
    r[2] = fmaxf(acc[2] * inv + bva.z, 0.f);
    r[3] = fmaxf(acc[3] * inv + bva.w, 0.f);
    r[4] = fmaxf(acc[4] * inv + bvb.x, 0.f);
    r[5] = fmaxf(acc[5] * inv + bvb.y, 0.f);
    r[6] = fmaxf(acc[6] * inv + bvb.z, 0.f);
    r[7] = fmaxf(acc[7] * inv + bvb.w, 0.f);

    // fused layer-2 projection: h2[k] = sum_c relu_out[c] * W2[c][k]
    float p0 = 0.f, p1 = 0.f;
#pragma unroll
    for (int k = 0; k < 4; ++k) {
        float4 w = *(const float4*)&W2[c0 * 2 + k * 4];   // rows c0+2k, c0+2k+1
        p0 += r[2 * k] * w.x + r[2 * k + 1] * w.z;
        p1 += r[2 * k] * w.y + r[2 * k + 1] * w.w;
    }
#pragma unroll
    for (int off = 1; off < 16; off <<= 1) {
        p0 += __shfl_xor(p0, off);
        p1 += __shfl_xor(p1, off);
    }
    if (lane == 0) {
        pk[wid] = make_float4(p0, p1,
                              p0 * a_src2[0] + p1 * a_src2[1],
                              p0 * a_dst2[0] + p1 * a_dst2[1]);
    }
}

// ---------------------------------------------------------------------------
// K4: layer-2 softmax-aggregation (1 head, 2 ch) + bias + log_softmax.
// 16 lanes per node (4 nodes per wave); single pass, no max shift.
// pk[s] = (h2_0, h2_1, a_s2, a_d2) -> one 16B gather per edge.
// ---------------------------------------------------------------------------
__global__ __launch_bounds__(256) void k4_agg2(
    const float4* __restrict__ pk, const int* __restrict__ row_start,
    const int* __restrict__ csr_src, const float* __restrict__ b2,
    float* __restrict__ out, int n) {
    const int g = blockIdx.x * blockDim.x + threadIdx.x;
    const int lane = threadIdx.x & 63;
    const int node = (g >> 6) * 4 + (lane >> 4);
    const int l16 = lane & 15;
    if (node >= n) return;
    const int rs = row_start[node];
    const int deg = row_start[node + 1] - rs;
    const float4 me = pk[node];
    const float ad = me.w;

    float dnm = 0.f, a0 = 0.f, a1 = 0.f;
    for (int j = l16; j < deg; j += 16) {
        int s = csr_src[rs + j];
        float4 qv = pk[s];
        float p = __expf(lrelu(qv.z + ad));
        dnm += p;
        a0 += p * qv.x;
        a1 += p * qv.y;
    }
    if (l16 == 0) {   // self-loop
        float p = __expf(lrelu(me.z + ad));
        dnm += p;
        a0 += p * me.x;
        a1 += p * me.y;
    }
#pragma unroll
    for (int off = 1; off < 16; off <<= 1) {
        dnm += __shfl_xor(dnm, off);
        a0 += __shfl_xor(a0, off);
        a1 += __shfl_xor(a1, off);
    }
    if (l16 == 0) {
        float inv = 1.f / (dnm + 1e-16f);
        float o0 = a0 * inv + b2[0];
        float o1 = a1 * inv + b2[1];
        float m2 = fmaxf(o0, o1);
        float lse = m2 + logf(__expf(o0 - m2) + __expf(o1 - m2));
        out[node * 2 + 0] = o0 - lse;
        out[node * 2 + 1] = o1 - lse;
    }
}

// ---------------------------------------------------------------------------
extern "C" void kernel_launch(void* const* d_in, const int* in_sizes, int n_in,
                              void* d_out, int out_size, void* d_ws, size_t ws_size,
                              hipStream_t stream) {
    const float* x      = (const float*)d_in[0];
    const int*   ei     = (const int*)d_in[1];
    const float* W1     = (const float*)d_in[2];
    const float* a_src1 = (const float*)d_in[3];
    const float* a_dst1 = (const float*)d_in[4];
    const float* b1     = (const float*)d_in[5];
    const float* W2     = (const float*)d_in[6];
    const float* a_src2 = (const float*)d_in[7];
    const float* a_dst2 = (const float*)d_in[8];
    const float* b2     = (const float*)d_in[9];
    float* out = (float*)d_out;

    const int N = in_sizes[0] / 128;
    const int E = in_sizes[1] / 2;
    const int* e_src = ei;        // edge_index[0]
    const int* e_dst = ei + E;    // edge_index[1]

    // ---- workspace carve (256B aligned)
    char* p = (char*)d_ws;
    auto alloc = [&](size_t bytes) -> void* {
        void* r = (void*)p;
        p += (bytes + 255) & ~(size_t)255;
        return r;
    };
    unsigned short* h1b = (unsigned short*)alloc((size_t)N * 128 * 2);
    float*  a_s1      = (float*)alloc((size_t)N * 4 * 4);
    float*  a_d1      = (float*)alloc((size_t)N * 4 * 4);
    float4* pk        = (float4*)alloc((size_t)N * 16);
    int*    counts    = (int*)alloc((size_t)N * 4);
    int*    cursor    = (int*)alloc((size_t)N * 4);
    int*    incl      = (int*)alloc((size_t)N * 4);
    int*    bsums     = (int*)alloc(256 * 4);
    int*    row_start = (int*)alloc((size_t)(N + 1) * 4);
    int*    csr_src   = (int*)alloc((size_t)E * 4);

    hipMemsetAsync(counts, 0, (size_t)N * 4, stream);

    const int NB = (N + 255) / 256;

    k1_gemm<<<(N + 31) / 32, 256, 0, stream>>>(x, W1, a_src1, a_dst1, h1b, a_s1, a_d1, N);

    k2_hist<<<(E + 255) / 256, 256, 0, stream>>>(e_dst, E, counts);
    k_scan1<<<NB, 256, 0, stream>>>(counts, N, incl, bsums);
    k_scan2<<<1, 256, 0, stream>>>(bsums, NB);
    k_scan3<<<NB, 256, 0, stream>>>(incl, bsums, counts, N, row_start, cursor);
    k2_scatter<<<(E + 255) / 256, 256, 0, stream>>>(e_src, e_dst, E, cursor, csr_src);

    k3_agg1<<<(N * 64 + 255) / 256, 256, 0, stream>>>(h1b, a_s1, a_d1, row_start, csr_src,
                                                      b1, W2, a_src2, a_dst2, pk, N);
    k4_agg2<<<((N + 3) / 4 * 64 + 255) / 256, 256, 0, stream>>>(pk, row_start, csr_src,
                                                                b2, out, N);
}

// Round 4
// 230.482 us; speedup vs baseline: 1.3555x; 1.0915x over previous
//
#include <hip/hip_runtime.h>
#include <hip/hip_bf16.h>

#define NEG_SLOPE 0.2f
#define BSH   6        // bucket = 64 dst nodes
#define BUKSZ 64
#define MAXBUK 1024    // supports N <= 65536
#define CHUNK 4096     // edges per partition block
#define CAP   2048     // LDS CSR capacity per half-bucket (mean ~512, 4x headroom)

__device__ __forceinline__ float lrelu(float v) {
    return v > 0.f ? v : NEG_SLOPE * v;
}

__device__ __forceinline__ unsigned short f2bf(float f) {   // RNE float->bf16
    unsigned int u = __float_as_uint(f);
    u = (u + 0x7fffu + ((u >> 16) & 1u)) >> 16;
    return (unsigned short)u;
}

__device__ __forceinline__ float2 bfpair(unsigned int u) {  // 2 packed bf16 -> 2 floats
    float2 r;
    r.x = __uint_as_float(u << 16);
    r.y = __uint_as_float(u & 0xffff0000u);
    return r;
}

// ---------------------------------------------------------------------------
// K1: h1b[N,128] (bf16) = x[N,128] @ W1[128,128]  (fp32 vector GEMM)
// + fused epilogue computing a_s1[n,h], a_d1[n,h] in fp32.
// ---------------------------------------------------------------------------
__global__ __launch_bounds__(256) void k1_gemm(const float* __restrict__ x,
                                               const float* __restrict__ W1,
                                               const float* __restrict__ a_src1,
                                               const float* __restrict__ a_dst1,
                                               unsigned short* __restrict__ h1b,
                                               float* __restrict__ a_s1,
                                               float* __restrict__ a_d1, int n) {
    __shared__ float xs[32][128];
    const int tid = threadIdx.x;
    const int row0 = blockIdx.x * 32;
    for (int i = 0; i < 4; ++i) {
        int f4 = tid + i * 256;          // 0..1023
        int r = f4 >> 5;
        int c = (f4 & 31) * 4;
        int gr = row0 + r;
        float4 v = make_float4(0.f, 0.f, 0.f, 0.f);
        if (gr < n) v = *(const float4*)&x[(size_t)gr * 128 + c];
        *(float4*)&xs[r][c] = v;
    }
    __syncthreads();
    const int tx = tid & 31;             // cols 4*tx..4*tx+3
    const int ty = tid >> 5;             // rows 4*ty..4*ty+3
    float acc[4][4] = {};
#pragma unroll 4
    for (int k = 0; k < 128; ++k) {
        float4 wv = *(const float4*)&W1[k * 128 + tx * 4];
        float xv[4];
#pragma unroll
        for (int r = 0; r < 4; ++r) xv[r] = xs[ty * 4 + r][k];
#pragma unroll
        for (int r = 0; r < 4; ++r) {
            acc[r][0] += xv[r] * wv.x;
            acc[r][1] += xv[r] * wv.y;
            acc[r][2] += xv[r] * wv.z;
            acc[r][3] += xv[r] * wv.w;
        }
    }
#pragma unroll
    for (int r = 0; r < 4; ++r) {
        int gr = row0 + ty * 4 + r;
        if (gr < n) {
            ushort4 v;
            v.x = f2bf(acc[r][0]);
            v.y = f2bf(acc[r][1]);
            v.z = f2bf(acc[r][2]);
            v.w = f2bf(acc[r][3]);
            *(ushort4*)&h1b[(size_t)gr * 128 + tx * 4] = v;
        }
    }
    // --- fused attention-dot epilogue (fp32) ---
    float4 asv = *(const float4*)&a_src1[tx * 4];
    float4 adv = *(const float4*)&a_dst1[tx * 4];
    float ps[4], pd[4];
#pragma unroll
    for (int r = 0; r < 4; ++r) {
        ps[r] = acc[r][0] * asv.x + acc[r][1] * asv.y + acc[r][2] * asv.z + acc[r][3] * asv.w;
        pd[r] = acc[r][0] * adv.x + acc[r][1] * adv.y + acc[r][2] * adv.z + acc[r][3] * adv.w;
    }
#pragma unroll
    for (int off = 1; off < 8; off <<= 1) {
#pragma unroll
        for (int r = 0; r < 4; ++r) {
            ps[r] += __shfl_xor(ps[r], off);
            pd[r] += __shfl_xor(pd[r], off);
        }
    }
    if ((tx & 7) == 0) {
        int hd = tx >> 3;
#pragma unroll
        for (int r = 0; r < 4; ++r) {
            int gr = row0 + ty * 4 + r;
            if (gr < n) {
                a_s1[gr * 4 + hd] = ps[r];
                a_d1[gr * 4 + hd] = pd[r];
            }
        }
    }
}

// ---------------------------------------------------------------------------
// Bucket partition: per-chunk histogram (LDS atomics) -> mat[i*nbuk+b]
// ---------------------------------------------------------------------------
__global__ __launch_bounds__(256) void kb_hist(const int* __restrict__ dst, int e,
                                               int nbuk, int* __restrict__ mat) {
    __shared__ int lcnt[MAXBUK];
    const int tid = threadIdx.x;
    for (int b = tid; b < nbuk; b += 256) lcnt[b] = 0;
    __syncthreads();
    const int e0 = blockIdx.x * CHUNK;
    const int e1 = min(e, e0 + CHUNK);
    for (int k = e0 + tid; k < e1; k += 256)
        atomicAdd(&lcnt[dst[k] >> BSH], 1);
    __syncthreads();
    for (int b = tid; b < nbuk; b += 256)
        mat[blockIdx.x * nbuk + b] = lcnt[b];   // coalesced row write
}

// Column scan: mat[i][b] -> exclusive over i (in place); column totals -> btot[b]
__global__ __launch_bounds__(256) void kc_colscan(int* __restrict__ mat, int nbuk, int nblk,
                                                  int* __restrict__ btot) {
    int b = blockIdx.x * 256 + threadIdx.x;
    if (b >= nbuk) return;
    int run = 0;
#pragma unroll 4
    for (int i = 0; i < nblk; ++i) {
        int idx = i * nbuk + b;
        int t = mat[idx];
        mat[idx] = run;
        run += t;
    }
    btot[b] = run;
}

// Exclusive scan of bucket totals -> bbase[0..nbuk] (bbase[nbuk] = E)
__global__ __launch_bounds__(256) void kc_bucketscan(const int* __restrict__ btot,
                                                     int nbuk, int* __restrict__ bbase) {
    __shared__ int s[256];
    __shared__ int carry;
    const int tid = threadIdx.x;
    if (tid == 0) carry = 0;
    __syncthreads();
    for (int base = 0; base < nbuk; base += 256) {
        int g = base + tid;
        int v = (g < nbuk) ? btot[g] : 0;
        s[tid] = v;
        __syncthreads();
        for (int off = 1; off < 256; off <<= 1) {
            int t = (tid >= off) ? s[tid - off] : 0;
            __syncthreads();
            s[tid] += t;
            __syncthreads();
        }
        if (g < nbuk) bbase[g] = carry + s[tid] - v;   // exclusive
        __syncthreads();
        if (tid == 255) carry += s[255];
        __syncthreads();
    }
    if (tid == 0) bbase[nbuk] = carry;
}

// Placement: LDS cursors seeded from bbase+mat; write packed (src<<16|dst)
__global__ __launch_bounds__(256) void kb_place(const int* __restrict__ src,
                                                const int* __restrict__ dst, int e,
                                                int nbuk, const int* __restrict__ mat,
                                                const int* __restrict__ bbase,
                                                unsigned int* __restrict__ part) {
    __shared__ int lcur[MAXBUK];
    const int tid = threadIdx.x;
    for (int b = tid; b < nbuk; b += 256)
        lcur[b] = bbase[b] + mat[blockIdx.x * nbuk + b];
    __syncthreads();
    const int e0 = blockIdx.x * CHUNK;
    const int e1 = min(e, e0 + CHUNK);
    for (int k = e0 + tid; k < e1; k += 256) {
        int d = dst[k];
        int pos = atomicAdd(&lcur[d >> BSH], 1);
        part[pos] = ((unsigned int)src[k] << 16) | (unsigned int)d;
    }
}

// ---------------------------------------------------------------------------
// K3: layer-1 softmax-aggregation. Block = half-bucket (32 dst nodes).
// Builds 32-row CSR in LDS from the bucket's contiguous edge run, then each
// wave processes 8 nodes (quarter-wave per edge; lane owns 8 bf16 channels).
// Fused: +bias, relu, layer-2 projection, layer-2 attn dots -> pk.
// ---------------------------------------------------------------------------
__global__ __launch_bounds__(256) void k3_agg1(
    const unsigned short* __restrict__ h1b, const float* __restrict__ a_s1,
    const float* __restrict__ a_d1, const unsigned int* __restrict__ part,
    const int* __restrict__ bbase, const float* __restrict__ b1,
    const float* __restrict__ W2, const float* __restrict__ a_src2,
    const float* __restrict__ a_dst2, float4* __restrict__ pk, int n) {
    __shared__ unsigned short ls[CAP];
    __shared__ int rsx[33];
    __shared__ int cnt[32];
    __shared__ int cur[32];
    const int b = blockIdx.x;
    const int half = blockIdx.y;
    const int tid = threadIdx.x;
    const int eb = bbase[b];
    const int nE = bbase[b + 1] - eb;
    if (tid < 32) cnt[tid] = 0;
    __syncthreads();
    for (int k = tid; k < nE; k += 256) {
        int dl = (int)(part[eb + k] & 63u);
        if ((dl >> 5) == half) atomicAdd(&cnt[dl & 31], 1);
    }
    __syncthreads();
    if (tid < 32) {                       // wave-0 inclusive scan of 32 counts
        int v = cnt[tid];
        int incl = v;
#pragma unroll
        for (int off = 1; off < 32; off <<= 1) {
            int t = __shfl_up(incl, off);
            if (tid >= off) incl += t;
        }
        rsx[tid + 1] = incl;
        cur[tid] = incl - v;
        if (tid == 0) rsx[0] = 0;
    }
    __syncthreads();
    for (int k = tid; k < nE; k += 256) {
        unsigned int u = part[eb + k];
        int dl = (int)(u & 63u);
        if ((dl >> 5) == half) {
            int pos = atomicAdd(&cur[dl & 31], 1);
            if (pos < CAP) ls[pos] = (unsigned short)(u >> 16);
        }
    }
    __syncthreads();

    const int w = tid >> 6;
    const int lane = tid & 63;
    const int q = lane >> 4;             // quarter: edge slot 0..3
    const int l16 = lane & 15;
    const int c0 = l16 * 8;              // 8 channels per lane
    const int head = l16 >> 2;           // 4 lanes per head

    for (int t8 = 0; t8 < 8; ++t8) {
        const int nl = w * 8 + t8;       // 0..31
        const int node = (b << BSH) + (half << 5) + nl;
        if (node >= n) continue;
        const int r0 = rsx[nl];
        const int deg = rsx[nl + 1] - r0;
        const float ad = a_d1[node * 4 + head];

        float dnm = 0.f;
        float acc[8] = {};
        int j = q;
        for (; j + 4 < deg; j += 8) {    // 2 edges per quarter per iter
            int s0 = ls[r0 + j];
            int s1 = ls[r0 + j + 4];
            float as0 = a_s1[s0 * 4 + head];
            float as1 = a_s1[s1 * 4 + head];
            uint4 g0 = *(const uint4*)&h1b[(size_t)s0 * 128 + c0];
            uint4 g1 = *(const uint4*)&h1b[(size_t)s1 * 128 + c0];
            float p0 = __expf(lrelu(as0 + ad));
            float p1 = __expf(lrelu(as1 + ad));
            dnm += p0 + p1;
            float2 h0a = bfpair(g0.x), h0b = bfpair(g0.y), h0c = bfpair(g0.z), h0d = bfpair(g0.w);
            float2 h1a = bfpair(g1.x), h1b2 = bfpair(g1.y), h1c = bfpair(g1.z), h1d = bfpair(g1.w);
            acc[0] += p0 * h0a.x + p1 * h1a.x;  acc[1] += p0 * h0a.y + p1 * h1a.y;
            acc[2] += p0 * h0b.x + p1 * h1b2.x; acc[3] += p0 * h0b.y + p1 * h1b2.y;
            acc[4] += p0 * h0c.x + p1 * h1c.x;  acc[5] += p0 * h0c.y + p1 * h1c.y;
            acc[6] += p0 * h0d.x + p1 * h1d.x;  acc[7] += p0 * h0d.y + p1 * h1d.y;
        }
        if (j < deg) {
            int s0 = ls[r0 + j];
            float as0 = a_s1[s0 * 4 + head];
            uint4 g0 = *(const uint4*)&h1b[(size_t)s0 * 128 + c0];
            float p0 = __expf(lrelu(as0 + ad));
            dnm += p0;
            float2 ha = bfpair(g0.x), hb = bfpair(g0.y), hc = bfpair(g0.z), hd2 = bfpair(g0.w);
            acc[0] += p0 * ha.x;  acc[1] += p0 * ha.y;
            acc[2] += p0 * hb.x;  acc[3] += p0 * hb.y;
            acc[4] += p0 * hc.x;  acc[5] += p0 * hc.y;
            acc[6] += p0 * hd2.x; acc[7] += p0 * hd2.y;
        }
        // combine quarters
        dnm += __shfl_xor(dnm, 16);
        dnm += __shfl_xor(dnm, 32);
#pragma unroll
        for (int k = 0; k < 8; ++k) {
            acc[k] += __shfl_xor(acc[k], 16);
            acc[k] += __shfl_xor(acc[k], 32);
        }
        // self-loop (uniform across quarters)
        {
            float p = __expf(lrelu(a_s1[node * 4 + head] + ad));
            uint4 g0 = *(const uint4*)&h1b[(size_t)node * 128 + c0];
            float2 ha = bfpair(g0.x), hb = bfpair(g0.y), hc = bfpair(g0.z), hd2 = bfpair(g0.w);
            dnm += p;
            acc[0] += p * ha.x;  acc[1] += p * ha.y;
            acc[2] += p * hb.x;  acc[3] += p * hb.y;
            acc[4] += p * hc.x;  acc[5] += p * hc.y;
            acc[6] += p * hd2.x; acc[7] += p * hd2.y;
        }
        float inv = 1.f / (dnm + 1e-16f);
        float r[8];
        float4 bva = *(const float4*)&b1[c0];
        float4 bvb = *(const float4*)&b1[c0 + 4];
        r[0] = fmaxf(acc[0] * inv + bva.x, 0.f);
        r[1] = fmaxf(acc[1] * inv + bva.y, 0.f);
        r[2] = fmaxf(acc[2] * inv + bva.z, 0.f);
        r[3] = fmaxf(acc[3] * inv + bva.w, 0.f);
        r[4] = fmaxf(acc[4] * inv + bvb.x, 0.f);
        r[5] = fmaxf(acc[5] * inv + bvb.y, 0.f);
        r[6] = fmaxf(acc[6] * inv + bvb.z, 0.f);
        r[7] = fmaxf(acc[7] * inv + bvb.w, 0.f);

        // fused layer-2 projection
        float p0 = 0.f, p1 = 0.f;
#pragma unroll
        for (int k = 0; k < 4; ++k) {
            float4 wv = *(const float4*)&W2[c0 * 2 + k * 4];
            p0 += r[2 * k] * wv.x + r[2 * k + 1] * wv.z;
            p1 += r[2 * k] * wv.y + r[2 * k + 1] * wv.w;
        }
#pragma unroll
        for (int off = 1; off < 16; off <<= 1) {
            p0 += __shfl_xor(p0, off);
            p1 += __shfl_xor(p1, off);
        }
        if (lane == 0) {
            pk[node] = make_float4(p0, p1,
                                   p0 * a_src2[0] + p1 * a_src2[1],
                                   p0 * a_dst2[0] + p1 * a_dst2[1]);
        }
    }
}

// ---------------------------------------------------------------------------
// K4: layer-2 softmax-aggregation + bias + log_softmax.
// Block = half-bucket; LDS float atomics per dst node (deg~16 contention).
// ---------------------------------------------------------------------------
__global__ __launch_bounds__(256) void k4_agg2(
    const float4* __restrict__ pk, const unsigned int* __restrict__ part,
    const int* __restrict__ bbase, const float* __restrict__ b2,
    float* __restrict__ out, int n) {
    __shared__ float dnm[32], s0a[32], s1a[32];
    __shared__ float4 lpk[32];
    const int b = blockIdx.x;
    const int half = blockIdx.y;
    const int tid = threadIdx.x;
    const int eb = bbase[b];
    const int nE = bbase[b + 1] - eb;
    if (tid < 32) {
        dnm[tid] = 0.f; s0a[tid] = 0.f; s1a[tid] = 0.f;
        int node = (b << BSH) + (half << 5) + tid;
        lpk[tid] = (node < n) ? pk[node] : make_float4(0.f, 0.f, 0.f, 0.f);
    }
    __syncthreads();
    for (int k = tid; k < nE; k += 256) {
        unsigned int u = part[eb + k];
        int dl = (int)(u & 63u);
        if ((dl >> 5) == half) {
            int dli = dl & 31;
            float4 qv = pk[u >> 16];
            float p = __expf(lrelu(qv.z + lpk[dli].w));
            atomicAdd(&dnm[dli], p);
            atomicAdd(&s0a[dli], p * qv.x);
            atomicAdd(&s1a[dli], p * qv.y);
        }
    }
    __syncthreads();
    if (tid < 32) {
        int node = (b << BSH) + (half << 5) + tid;
        if (node < n) {
            float4 me = lpk[tid];
            float p = __expf(lrelu(me.z + me.w));      // self-loop
            float dn = dnm[tid] + p;
            float a0 = s0a[tid] + p * me.x;
            float a1 = s1a[tid] + p * me.y;
            float inv = 1.f / (dn + 1e-16f);
            float o0 = a0 * inv + b2[0];
            float o1 = a1 * inv + b2[1];
            float m2 = fmaxf(o0, o1);
            float lse = m2 + logf(__expf(o0 - m2) + __expf(o1 - m2));
            out[node * 2 + 0] = o0 - lse;
            out[node * 2 + 1] = o1 - lse;
        }
    }
}

// ---------------------------------------------------------------------------
extern "C" void kernel_launch(void* const* d_in, const int* in_sizes, int n_in,
                              void* d_out, int out_size, void* d_ws, size_t ws_size,
                              hipStream_t stream) {
    const float* x      = (const float*)d_in[0];
    const int*   ei     = (const int*)d_in[1];
    const float* W1     = (const float*)d_in[2];
    const float* a_src1 = (const float*)d_in[3];
    const float* a_dst1 = (const float*)d_in[4];
    const float* b1     = (const float*)d_in[5];
    const float* W2     = (const float*)d_in[6];
    const float* a_src2 = (const float*)d_in[7];
    const float* a_dst2 = (const float*)d_in[8];
    const float* b2     = (const float*)d_in[9];
    float* out = (float*)d_out;

    const int N = in_sizes[0] / 128;
    const int E = in_sizes[1] / 2;
    const int* e_src = ei;        // edge_index[0]
    const int* e_dst = ei + E;    // edge_index[1]

    const int NBUK = (N + BUKSZ - 1) >> BSH;     // 782 for N=50000
    const int nblk = (E + CHUNK - 1) / CHUNK;    // 196 for E=800000

    // ---- workspace carve (256B aligned)
    char* p = (char*)d_ws;
    auto alloc = [&](size_t bytes) -> void* {
        void* r = (void*)p;
        p += (bytes + 255) & ~(size_t)255;
        return r;
    };
    unsigned short* h1b  = (unsigned short*)alloc((size_t)N * 128 * 2);
    float*        a_s1   = (float*)alloc((size_t)N * 4 * 4);
    float*        a_d1   = (float*)alloc((size_t)N * 4 * 4);
    float4*       pk     = (float4*)alloc((size_t)N * 16);
    int*          mat    = (int*)alloc((size_t)NBUK * nblk * 4);
    int*          btot   = (int*)alloc((size_t)NBUK * 4);
    int*          bbase  = (int*)alloc((size_t)(NBUK + 1) * 4);
    unsigned int* part   = (unsigned int*)alloc((size_t)E * 4);

    k1_gemm<<<(N + 31) / 32, 256, 0, stream>>>(x, W1, a_src1, a_dst1, h1b, a_s1, a_d1, N);

    kb_hist<<<nblk, 256, 0, stream>>>(e_dst, E, NBUK, mat);
    kc_colscan<<<(NBUK + 255) / 256, 256, 0, stream>>>(mat, NBUK, nblk, btot);
    kc_bucketscan<<<1, 256, 0, stream>>>(btot, NBUK, bbase);
    kb_place<<<nblk, 256, 0, stream>>>(e_src, e_dst, E, NBUK, mat, bbase, part);

    k3_agg1<<<dim3(NBUK, 2), 256, 0, stream>>>(h1b, a_s1, a_d1, part, bbase,
                                               b1, W2, a_src2, a_dst2, pk, N);
    k4_agg2<<<dim3(NBUK, 2), 256, 0, stream>>>(pk, part, bbase, b2, out, N);
}

// Round 5
// 221.703 us; speedup vs baseline: 1.4092x; 1.0396x over previous
//
#include <hip/hip_runtime.h>
#include <hip/hip_bf16.h>

#define NEG_SLOPE 0.2f
#define BSH   6        // bucket = 64 dst nodes
#define BUKSZ 64
#define MAXBUK 1024    // supports N <= 65536 (and src ids fit in ushort)
#define CHUNK 4096     // edges per partition block
#define BCAP  2048     // LDS capacity per bucket in kc_csr (mean ~1024, 2x headroom)

__device__ __forceinline__ float lrelu(float v) {
    return v > 0.f ? v : NEG_SLOPE * v;
}

__device__ __forceinline__ unsigned short f2bf(float f) {   // RNE float->bf16
    unsigned int u = __float_as_uint(f);
    u = (u + 0x7fffu + ((u >> 16) & 1u)) >> 16;
    return (unsigned short)u;
}

__device__ __forceinline__ float2 bfpair(unsigned int u) {  // 2 packed bf16 -> 2 floats
    float2 r;
    r.x = __uint_as_float(u << 16);
    r.y = __uint_as_float(u & 0xffff0000u);
    return r;
}

// ---------------------------------------------------------------------------
// K1: h1b[N,128] (bf16) = x[N,128] @ W1[128,128]  (fp32 vector GEMM)
// + fused epilogue computing a_s1[n,h], a_d1[n,h] in fp32.
// ---------------------------------------------------------------------------
__global__ __launch_bounds__(256) void k1_gemm(const float* __restrict__ x,
                                               const float* __restrict__ W1,
                                               const float* __restrict__ a_src1,
                                               const float* __restrict__ a_dst1,
                                               unsigned short* __restrict__ h1b,
                                               float* __restrict__ a_s1,
                                               float* __restrict__ a_d1, int n) {
    __shared__ float xs[32][128];
    const int tid = threadIdx.x;
    const int row0 = blockIdx.x * 32;
    for (int i = 0; i < 4; ++i) {
        int f4 = tid + i * 256;          // 0..1023
        int r = f4 >> 5;
        int c = (f4 & 31) * 4;
        int gr = row0 + r;
        float4 v = make_float4(0.f, 0.f, 0.f, 0.f);
        if (gr < n) v = *(const float4*)&x[(size_t)gr * 128 + c];
        *(float4*)&xs[r][c] = v;
    }
    __syncthreads();
    const int tx = tid & 31;             // cols 4*tx..4*tx+3
    const int ty = tid >> 5;             // rows 4*ty..4*ty+3
    float acc[4][4] = {};
#pragma unroll 4
    for (int k = 0; k < 128; ++k) {
        float4 wv = *(const float4*)&W1[k * 128 + tx * 4];
        float xv[4];
#pragma unroll
        for (int r = 0; r < 4; ++r) xv[r] = xs[ty * 4 + r][k];
#pragma unroll
        for (int r = 0; r < 4; ++r) {
            acc[r][0] += xv[r] * wv.x;
            acc[r][1] += xv[r] * wv.y;
            acc[r][2] += xv[r] * wv.z;
            acc[r][3] += xv[r] * wv.w;
        }
    }
#pragma unroll
    for (int r = 0; r < 4; ++r) {
        int gr = row0 + ty * 4 + r;
        if (gr < n) {
            ushort4 v;
            v.x = f2bf(acc[r][0]);
            v.y = f2bf(acc[r][1]);
            v.z = f2bf(acc[r][2]);
            v.w = f2bf(acc[r][3]);
            *(ushort4*)&h1b[(size_t)gr * 128 + tx * 4] = v;
        }
    }
    // --- fused attention-dot epilogue (fp32) ---
    float4 asv = *(const float4*)&a_src1[tx * 4];
    float4 adv = *(const float4*)&a_dst1[tx * 4];
    float ps[4], pd[4];
#pragma unroll
    for (int r = 0; r < 4; ++r) {
        ps[r] = acc[r][0] * asv.x + acc[r][1] * asv.y + acc[r][2] * asv.z + acc[r][3] * asv.w;
        pd[r] = acc[r][0] * adv.x + acc[r][1] * adv.y + acc[r][2] * adv.z + acc[r][3] * adv.w;
    }
#pragma unroll
    for (int off = 1; off < 8; off <<= 1) {
#pragma unroll
        for (int r = 0; r < 4; ++r) {
            ps[r] += __shfl_xor(ps[r], off);
            pd[r] += __shfl_xor(pd[r], off);
        }
    }
    if ((tx & 7) == 0) {
        int hd = tx >> 3;
#pragma unroll
        for (int r = 0; r < 4; ++r) {
            int gr = row0 + ty * 4 + r;
            if (gr < n) {
                a_s1[gr * 4 + hd] = ps[r];
                a_d1[gr * 4 + hd] = pd[r];
            }
        }
    }
}

// ---------------------------------------------------------------------------
// Bucket partition: per-chunk histogram (LDS atomics) -> mat[i*nbuk+b]
// ---------------------------------------------------------------------------
__global__ __launch_bounds__(256) void kb_hist(const int* __restrict__ dst, int e,
                                               int nbuk, int* __restrict__ mat) {
    __shared__ int lcnt[MAXBUK];
    const int tid = threadIdx.x;
    for (int b = tid; b < nbuk; b += 256) lcnt[b] = 0;
    __syncthreads();
    const int e0 = blockIdx.x * CHUNK;
    const int e1 = min(e, e0 + CHUNK);
    for (int k = e0 + tid; k < e1; k += 256)
        atomicAdd(&lcnt[dst[k] >> BSH], 1);
    __syncthreads();
    for (int b = tid; b < nbuk; b += 256)
        mat[blockIdx.x * nbuk + b] = lcnt[b];   // coalesced row write
}

// Column scan: mat[i][b] -> exclusive over i (in place); column totals -> btot[b]
__global__ __launch_bounds__(256) void kc_colscan(int* __restrict__ mat, int nbuk, int nblk,
                                                  int* __restrict__ btot) {
    int b = blockIdx.x * 256 + threadIdx.x;
    if (b >= nbuk) return;
    int run = 0;
#pragma unroll 4
    for (int i = 0; i < nblk; ++i) {
        int idx = i * nbuk + b;
        int t = mat[idx];
        mat[idx] = run;
        run += t;
    }
    btot[b] = run;
}

// Exclusive scan of bucket totals -> bbase[0..nbuk] (bbase[nbuk] = E)
__global__ __launch_bounds__(256) void kc_bucketscan(const int* __restrict__ btot,
                                                     int nbuk, int* __restrict__ bbase) {
    __shared__ int s[256];
    __shared__ int carry;
    const int tid = threadIdx.x;
    if (tid == 0) carry = 0;
    __syncthreads();
    for (int base = 0; base < nbuk; base += 256) {
        int g = base + tid;
        int v = (g < nbuk) ? btot[g] : 0;
        s[tid] = v;
        __syncthreads();
        for (int off = 1; off < 256; off <<= 1) {
            int t = (tid >= off) ? s[tid - off] : 0;
            __syncthreads();
            s[tid] += t;
            __syncthreads();
        }
        if (g < nbuk) bbase[g] = carry + s[tid] - v;   // exclusive
        __syncthreads();
        if (tid == 255) carry += s[255];
        __syncthreads();
    }
    if (tid == 0) bbase[nbuk] = carry;
}

// Placement: LDS cursors seeded from bbase+mat; write packed (src<<16|dst&63...)
// part[pos] = src<<16 | dst (dst low 16 bits; only low 6 needed downstream)
__global__ __launch_bounds__(256) void kb_place(const int* __restrict__ src,
                                                const int* __restrict__ dst, int e,
                                                int nbuk, const int* __restrict__ mat,
                                                const int* __restrict__ bbase,
                                                unsigned int* __restrict__ part) {
    __shared__ int lcur[MAXBUK];
    const int tid = threadIdx.x;
    for (int b = tid; b < nbuk; b += 256)
        lcur[b] = bbase[b] + mat[blockIdx.x * nbuk + b];
    __syncthreads();
    const int e0 = blockIdx.x * CHUNK;
    const int e1 = min(e, e0 + CHUNK);
    for (int k = e0 + tid; k < e1; k += 256) {
        int d = dst[k];
        int pos = atomicAdd(&lcur[d >> BSH], 1);
        part[pos] = ((unsigned int)src[k] << 16) | (unsigned int)(d & 0xffff);
    }
}

// ---------------------------------------------------------------------------
// CSR finalize: block per bucket. Reads the bucket's contiguous part[] run,
// builds per-node (64) CSR in LDS, writes row_start (int, absolute) and
// csr_src (ushort) coalesced. Hot kernels then need no LDS build at all.
// ---------------------------------------------------------------------------
__global__ __launch_bounds__(256) void kc_csr(const unsigned int* __restrict__ part,
                                              const int* __restrict__ bbase, int nbuk,
                                              int* __restrict__ row_start,
                                              unsigned short* __restrict__ csr_src) {
    __shared__ unsigned short ls[BCAP];
    __shared__ int cnt[64];
    __shared__ int cur[64];
    const int b = blockIdx.x;
    const int tid = threadIdx.x;
    const int eb = bbase[b];
    const int nE = bbase[b + 1] - eb;
    if (tid < 64) cnt[tid] = 0;
    __syncthreads();
    for (int k = tid; k < nE; k += 256)
        atomicAdd(&cnt[part[eb + k] & 63u], 1);
    __syncthreads();
    if (tid < 64) {                       // wave-0 exclusive scan of 64 counts
        int v = cnt[tid];
        int incl = v;
#pragma unroll
        for (int off = 1; off < 64; off <<= 1) {
            int t = __shfl_up(incl, off);
            if (tid >= off) incl += t;
        }
        int excl = incl - v;
        cur[tid] = excl;
        row_start[(b << BSH) + tid] = eb + excl;
        if (tid == 63 && b == nbuk - 1) row_start[(b << BSH) + 64] = eb + incl;
    }
    __syncthreads();
    for (int k = tid; k < nE; k += 256) {
        unsigned int u = part[eb + k];
        int pos = atomicAdd(&cur[u & 63u], 1);
        if (pos < BCAP) ls[pos] = (unsigned short)(u >> 16);
    }
    __syncthreads();
    for (int k = tid; k < nE; k += 256)
        csr_src[eb + k] = ls[k];          // coalesced
}

// ---------------------------------------------------------------------------
// K3: layer-1 softmax-aggregation, flat: one wave per dst node.
// Quarter-wave per edge (4 edges in flight, unroll 2 -> 8 gather chains).
// Lane owns 8 bf16 channels (16B gather). Single pass, no max shift (logits
// bounded; alpha = p/Σp shift-invariant).
// Fused: +bias, relu, layer-2 projection, layer-2 attn dots ->
// pk[node] = (h2_0, h2_1, a_s2, a_d2).
// ---------------------------------------------------------------------------
__global__ __launch_bounds__(256) void k3_agg1(
    const unsigned short* __restrict__ h1b, const float* __restrict__ a_s1,
    const float* __restrict__ a_d1, const int* __restrict__ row_start,
    const unsigned short* __restrict__ csr_src, const float* __restrict__ b1,
    const float* __restrict__ W2, const float* __restrict__ a_src2,
    const float* __restrict__ a_dst2, float4* __restrict__ pk, int n) {
    const int wid = (blockIdx.x * blockDim.x + threadIdx.x) >> 6;
    const int lane = threadIdx.x & 63;
    if (wid >= n) return;
    const int q = lane >> 4;             // quarter: edge slot 0..3
    const int l16 = lane & 15;
    const int c0 = l16 * 8;              // 8 channels per lane
    const int head = l16 >> 2;           // 4 lanes per head
    const int rs = row_start[wid];
    const int deg = row_start[wid + 1] - rs;
    const float ad = a_d1[wid * 4 + head];

    float dnm = 0.f;
    float acc[8] = {};
    int j = q;
    for (; j + 4 < deg; j += 8) {        // 2 edges per quarter per iter
        int s0 = (int)csr_src[rs + j];
        int s1 = (int)csr_src[rs + j + 4];
        float as0 = a_s1[s0 * 4 + head];
        float as1 = a_s1[s1 * 4 + head];
        uint4 g0 = *(const uint4*)&h1b[(size_t)s0 * 128 + c0];
        uint4 g1 = *(const uint4*)&h1b[(size_t)s1 * 128 + c0];
        float p0 = __expf(lrelu(as0 + ad));
        float p1 = __expf(lrelu(as1 + ad));
        dnm += p0 + p1;
        float2 h0a = bfpair(g0.x), h0b = bfpair(g0.y), h0c = bfpair(g0.z), h0d = bfpair(g0.w);
        float2 h1a = bfpair(g1.x), h1b2 = bfpair(g1.y), h1c = bfpair(g1.z), h1d = bfpair(g1.w);
        acc[0] += p0 * h0a.x + p1 * h1a.x;  acc[1] += p0 * h0a.y + p1 * h1a.y;
        acc[2] += p0 * h0b.x + p1 * h1b2.x; acc[3] += p0 * h0b.y + p1 * h1b2.y;
        acc[4] += p0 * h0c.x + p1 * h1c.x;  acc[5] += p0 * h0c.y + p1 * h1c.y;
        acc[6] += p0 * h0d.x + p1 * h1d.x;  acc[7] += p0 * h0d.y + p1 * h1d.y;
    }
    if (j < deg) {
        int s0 = (int)csr_src[rs + j];
        float as0 = a_s1[s0 * 4 + head];
        uint4 g0 = *(const uint4*)&h1b[(size_t)s0 * 128 + c0];
        float p0 = __expf(lrelu(as0 + ad));
        dnm += p0;
        float2 ha = bfpair(g0.x), hb = bfpair(g0.y), hc = bfpair(g0.z), hd2 = bfpair(g0.w);
        acc[0] += p0 * ha.x;  acc[1] += p0 * ha.y;
        acc[2] += p0 * hb.x;  acc[3] += p0 * hb.y;
        acc[4] += p0 * hc.x;  acc[5] += p0 * hc.y;
        acc[6] += p0 * hd2.x; acc[7] += p0 * hd2.y;
    }
    // combine quarters (lanes l16, l16+16, l16+32, l16+48 share channels/head)
    dnm += __shfl_xor(dnm, 16);
    dnm += __shfl_xor(dnm, 32);
#pragma unroll
    for (int k = 0; k < 8; ++k) {
        acc[k] += __shfl_xor(acc[k], 16);
        acc[k] += __shfl_xor(acc[k], 32);
    }
    // self-loop (uniform across quarters)
    {
        float p = __expf(lrelu(a_s1[wid * 4 + head] + ad));
        uint4 g0 = *(const uint4*)&h1b[(size_t)wid * 128 + c0];
        float2 ha = bfpair(g0.x), hb = bfpair(g0.y), hc = bfpair(g0.z), hd2 = bfpair(g0.w);
        dnm += p;
        acc[0] += p * ha.x;  acc[1] += p * ha.y;
        acc[2] += p * hb.x;  acc[3] += p * hb.y;
        acc[4] += p * hc.x;  acc[5] += p * hc.y;
        acc[6] += p * hd2.x; acc[7] += p * hd2.y;
    }
    float inv = 1.f / (dnm + 1e-16f);
    float r[8];
    float4 bva = *(const float4*)&b1[c0];
    float4 bvb = *(const float4*)&b1[c0 + 4];
    r[0] = fmaxf(acc[0] * inv + bva.x, 0.f);
    r[1] = fmaxf(acc[1] * inv + bva.y, 0.f);
    r[2] = fmaxf(acc[2] * inv + bva.z, 0.f);
    r[3] = fmaxf(acc[3] * inv + bva.w, 0.f);
    r[4] = fmaxf(acc[4] * inv + bvb.x, 0.f);
    r[5] = fmaxf(acc[5] * inv + bvb.y, 0.f);
    r[6] = fmaxf(acc[6] * inv + bvb.z, 0.f);
    r[7] = fmaxf(acc[7] * inv + bvb.w, 0.f);

    // fused layer-2 projection: h2[k] = sum_c relu_out[c] * W2[c][k]
    float p0 = 0.f, p1 = 0.f;
#pragma unroll
    for (int k = 0; k < 4; ++k) {
        float4 w = *(const float4*)&W2[c0 * 2 + k * 4];   // rows c0+2k, c0+2k+1
        p0 += r[2 * k] * w.x + r[2 * k + 1] * w.z;
        p1 += r[2 * k] * w.y + r[2 * k + 1] * w.w;
    }
#pragma unroll
    for (int off = 1; off < 16; off <<= 1) {
        p0 += __shfl_xor(p0, off);
        p1 += __shfl_xor(p1, off);
    }
    if (lane == 0) {
        pk[wid] = make_float4(p0, p1,
                              p0 * a_src2[0] + p1 * a_src2[1],
                              p0 * a_dst2[0] + p1 * a_dst2[1]);
    }
}

// ---------------------------------------------------------------------------
// K4: layer-2 softmax-aggregation (1 head, 2 ch) + bias + log_softmax.
// 16 lanes per node (4 nodes per wave); single pass, no max shift.
// pk[s] = (h2_0, h2_1, a_s2, a_d2) -> one 16B gather per edge.
// ---------------------------------------------------------------------------
__global__ __launch_bounds__(256) void k4_agg2(
    const float4* __restrict__ pk, const int* __restrict__ row_start,
    const unsigned short* __restrict__ csr_src, const float* __restrict__ b2,
    float* __restrict__ out, int n) {
    const int g = blockIdx.x * blockDim.x + threadIdx.x;
    const int lane = threadIdx.x & 63;
    const int node = (g >> 6) * 4 + (lane >> 4);
    const int l16 = lane & 15;
    if (node >= n) return;
    const int rs = row_start[node];
    const int deg = row_start[node + 1] - rs;
    const float4 me = pk[node];
    const float ad = me.w;

    float dnm = 0.f, a0 = 0.f, a1 = 0.f;
    for (int j = l16; j < deg; j += 16) {
        int s = (int)csr_src[rs + j];
        float4 qv = pk[s];
        float p = __expf(lrelu(qv.z + ad));
        dnm += p;
        a0 += p * qv.x;
        a1 += p * qv.y;
    }
    if (l16 == 0) {   // self-loop
        float p = __expf(lrelu(me.z + ad));
        dnm += p;
        a0 += p * me.x;
        a1 += p * me.y;
    }
#pragma unroll
    for (int off = 1; off < 16; off <<= 1) {
        dnm += __shfl_xor(dnm, off);
        a0 += __shfl_xor(a0, off);
        a1 += __shfl_xor(a1, off);
    }
    if (l16 == 0) {
        float inv = 1.f / (dnm + 1e-16f);
        float o0 = a0 * inv + b2[0];
        float o1 = a1 * inv + b2[1];
        float m2 = fmaxf(o0, o1);
        float lse = m2 + logf(__expf(o0 - m2) + __expf(o1 - m2));
        out[node * 2 + 0] = o0 - lse;
        out[node * 2 + 1] = o1 - lse;
    }
}

// ---------------------------------------------------------------------------
extern "C" void kernel_launch(void* const* d_in, const int* in_sizes, int n_in,
                              void* d_out, int out_size, void* d_ws, size_t ws_size,
                              hipStream_t stream) {
    const float* x      = (const float*)d_in[0];
    const int*   ei     = (const int*)d_in[1];
    const float* W1     = (const float*)d_in[2];
    const float* a_src1 = (const float*)d_in[3];
    const float* a_dst1 = (const float*)d_in[4];
    const float* b1     = (const float*)d_in[5];
    const float* W2     = (const float*)d_in[6];
    const float* a_src2 = (const float*)d_in[7];
    const float* a_dst2 = (const float*)d_in[8];
    const float* b2     = (const float*)d_in[9];
    float* out = (float*)d_out;

    const int N = in_sizes[0] / 128;
    const int E = in_sizes[1] / 2;
    const int* e_src = ei;        // edge_index[0]
    const int* e_dst = ei + E;    // edge_index[1]

    const int NBUK = (N + BUKSZ - 1) >> BSH;     // 782 for N=50000
    const int nblk = (E + CHUNK - 1) / CHUNK;    // 196 for E=800000

    // ---- workspace carve (256B aligned)
    char* p = (char*)d_ws;
    auto alloc = [&](size_t bytes) -> void* {
        void* r = (void*)p;
        p += (bytes + 255) & ~(size_t)255;
        return r;
    };
    unsigned short* h1b   = (unsigned short*)alloc((size_t)N * 128 * 2);
    float*          a_s1  = (float*)alloc((size_t)N * 4 * 4);
    float*          a_d1  = (float*)alloc((size_t)N * 4 * 4);
    float4*         pk    = (float4*)alloc((size_t)N * 16);
    int*            mat   = (int*)alloc((size_t)NBUK * nblk * 4);
    int*            btot  = (int*)alloc((size_t)NBUK * 4);
    int*            bbase = (int*)alloc((size_t)(NBUK + 1) * 4);
    unsigned int*   part  = (unsigned int*)alloc((size_t)E * 4);
    int*            row_start = (int*)alloc(((size_t)NBUK * BUKSZ + 1) * 4);
    unsigned short* csr_src   = (unsigned short*)alloc((size_t)E * 2);

    k1_gemm<<<(N + 31) / 32, 256, 0, stream>>>(x, W1, a_src1, a_dst1, h1b, a_s1, a_d1, N);

    kb_hist<<<nblk, 256, 0, stream>>>(e_dst, E, NBUK, mat);
    kc_colscan<<<(NBUK + 255) / 256, 256, 0, stream>>>(mat, NBUK, nblk, btot);
    kc_bucketscan<<<1, 256, 0, stream>>>(btot, NBUK, bbase);
    kb_place<<<nblk, 256, 0, stream>>>(e_src, e_dst, E, NBUK, mat, bbase, part);
    kc_csr<<<NBUK, 256, 0, stream>>>(part, bbase, NBUK, row_start, csr_src);

    k3_agg1<<<(N * 64 + 255) / 256, 256, 0, stream>>>(h1b, a_s1, a_d1, row_start, csr_src,
                                                      b1, W2, a_src2, a_dst2, pk, N);
    k4_agg2<<<((N + 3) / 4 * 64 + 255) / 256, 256, 0, stream>>>(pk, row_start, csr_src,
                                                                b2, out, N);
}